// Round 11
// baseline (616.862 us; speedup 1.0000x reference)
//
#include <hip/hip_runtime.h>

// SelfAttention_33852932227207 — MI355X, round 10 (resubmit; r10 bench was an
// infra failure: UnresponsiveContainer before first message).
// e = x^T (Wq^T Wa Wk) x / sqrt(512);  out = softmax(e) @ (x (Wb Wv)^T).
// GEMM core rebuilt for LDS/MFMA pipe overlap. Diagnosis: 2ph and 8ph both
// alternate {all-waves ds_read burst} <-> {all-waves MFMA burst}
// (lgkm0 before each cluster + lockstep barriers) -> 20% MfmaUtil. New core:
// fragments for tile T+1 are ds_read DURING tile T (regs double-buffered),
// MFMAs consume registers only, ONE vmcnt(0)+lgkm(0)+barrier per K-tile,
// staging T+2 issued at tile start. LDS reads now overlap MFMA within and
// across waves. Same MFMA order per accumulator -> bit-identical output.

typedef __attribute__((ext_vector_type(8))) short b16x8;
typedef __attribute__((ext_vector_type(4))) float f4;
typedef unsigned short u16;

#define DEVINL __device__ __forceinline__

DEVINL u16 f2bf(float f) {               // fp32 -> bf16 RNE
  unsigned int u = __float_as_uint(f);
  u = u + 0x7FFFu + ((u >> 16) & 1u);
  return (u16)(u >> 16);
}
DEVINL float bf2f(u16 h) { return __uint_as_float(((unsigned int)h) << 16); }

DEVINL f4 mfma_(b16x8 a, b16x8 b, f4 c) {
  return __builtin_amdgcn_mfma_f32_16x16x32_bf16(a, b, c, 0, 0, 0);
}
// bf16x3: (ah+al)*(bh+bl) ~= ah*bh + ah*bl + al*bh
DEVINL f4 mfma3(b16x8 ah, b16x8 al, b16x8 bh, b16x8 bl, f4 c) {
  c = mfma_(ah, bh, c);
  c = mfma_(ah, bl, c);
  c = mfma_(al, bh, c);
  return c;
}
DEVINL void gload16(const u16* g, u16* l) {
  __builtin_amdgcn_global_load_lds(
      (const __attribute__((address_space(1))) void*)g,
      (__attribute__((address_space(3))) void*)l, 16, 0, 0);
}

// ---- tile helpers, 16B-chunk XOR swizzle (r5-proven, bank-conflict=0).
DEVINL void stage_tile(const u16* __restrict__ gbase, int rstride,
                       u16* __restrict__ lds, int t) {
#pragma unroll
  for (int r = 0; r < 4; ++r) {
    int cp = r * 256 + t;
    int row = cp >> 3, j = cp & 7;
    int jj = j ^ (row & 7);
    gload16(&gbase[(size_t)row * rstride + jj * 8], &lds[cp * 8]);
  }
}
// 256x64 tile, 512 threads, 4 loads/thread.
DEVINL void stage256(const u16* __restrict__ gbase, int rstride,
                     u16* __restrict__ lds, int t) {
#pragma unroll
  for (int r = 0; r < 4; ++r) {
    int cp = r * 512 + t;                // chunk 0..2047
    int row = cp >> 3, j = cp & 7;
    int jj = j ^ (row & 7);
    gload16(&gbase[(size_t)row * rstride + jj * 8], &lds[cp * 8]);
  }
}
DEVINL b16x8 readfrag(const u16* __restrict__ lds, int row, int kk, int g) {
  int chunk = row * 8 + ((kk * 4 + g) ^ (row & 7));
  return *(const b16x8*)&lds[chunk * 8];
}

// ---- 256x256 BK=64 8-wave GEMM core, reads-one-tile-ahead.
// Per tile T: stage T+2 -> buf[T&1]; 4 MFMA clusters consume regs F(T);
// ds_read F(T+1) from buf[(T+1)&1] between clusters; one fence+barrier.
#define GEMM_TILE(A0c, B0c, A1c, B1c, A0n, B0n, A1n, B1n, stA, stB, rdA, rdB, T) \
  {                                                                              \
    if ((T) + 2 < NT) {                                                          \
      stage256(Ab + ((T) + 2) * 64, sA, (stA), t);                               \
      stage256(Bb + ((T) + 2) * 64, sB, (stB), t);                               \
    }                                                                            \
    __builtin_amdgcn_s_setprio(1);                                               \
    _Pragma("unroll") for (int rt = 0; rt < 8; ++rt) {                           \
      acc[rt][0] = mfma_(A0c[rt], B0c[0], acc[rt][0]);                           \
      acc[rt][1] = mfma_(A0c[rt], B0c[1], acc[rt][1]);                           \
    }                                                                            \
    __builtin_amdgcn_s_setprio(0);                                               \
    if ((T) + 1 < NT) {                                                          \
      _Pragma("unroll") for (int rt = 0; rt < 8; ++rt)                           \
          A0n[rt] = readfrag((rdA), wr * 128 + rt * 16 + ql, 0, g);              \
      _Pragma("unroll") for (int ct = 0; ct < 4; ++ct)                           \
          B0n[ct] = readfrag((rdB), wc * 64 + ct * 16 + ql, 0, g);               \
    }                                                                            \
    __builtin_amdgcn_s_setprio(1);                                               \
    _Pragma("unroll") for (int rt = 0; rt < 8; ++rt) {                           \
      acc[rt][2] = mfma_(A0c[rt], B0c[2], acc[rt][2]);                           \
      acc[rt][3] = mfma_(A0c[rt], B0c[3], acc[rt][3]);                           \
    }                                                                            \
    __builtin_amdgcn_s_setprio(0);                                               \
    if ((T) + 1 < NT) {                                                          \
      _Pragma("unroll") for (int rt = 0; rt < 8; ++rt)                           \
          A1n[rt] = readfrag((rdA), wr * 128 + rt * 16 + ql, 1, g);              \
      _Pragma("unroll") for (int ct = 0; ct < 4; ++ct)                           \
          B1n[ct] = readfrag((rdB), wc * 64 + ct * 16 + ql, 1, g);               \
    }                                                                            \
    __builtin_amdgcn_s_setprio(1);                                               \
    _Pragma("unroll") for (int rt = 0; rt < 8; ++rt) {                           \
      acc[rt][0] = mfma_(A1c[rt], B1c[0], acc[rt][0]);                           \
      acc[rt][1] = mfma_(A1c[rt], B1c[1], acc[rt][1]);                           \
      acc[rt][2] = mfma_(A1c[rt], B1c[2], acc[rt][2]);                           \
      acc[rt][3] = mfma_(A1c[rt], B1c[3], acc[rt][3]);                           \
    }                                                                            \
    __builtin_amdgcn_s_setprio(0);                                               \
    asm volatile("s_waitcnt vmcnt(0) lgkmcnt(0)" ::: "memory");                  \
    __builtin_amdgcn_s_barrier();                                                \
  }

template <int NT>
DEVINL void gemm256_core(const u16* __restrict__ Ab, int sA,
                         const u16* __restrict__ Bb, int sB,
                         u16* __restrict__ ldsA, u16* __restrict__ ldsB,
                         int t, int wr, int wc, int ql, int g, f4 acc[8][4]) {
  b16x8 A0a[8], B0a[4], A1a[8], B1a[4];
  b16x8 A0b[8], B0b[4], A1b[8], B1b[4];
  // prologue: tile0 -> buf0, tile1 -> buf1; validate buf0; read F(0); validate buf1.
  stage256(Ab, sA, ldsA, t);
  stage256(Bb, sB, ldsB, t);
  stage256(Ab + 64, sA, ldsA + 16384, t);
  stage256(Bb + 64, sB, ldsB + 16384, t);
  asm volatile("s_waitcnt vmcnt(8)" ::: "memory");
  __builtin_amdgcn_s_barrier();
#pragma unroll
  for (int rt = 0; rt < 8; ++rt) {
    A0a[rt] = readfrag(ldsA, wr * 128 + rt * 16 + ql, 0, g);
    A1a[rt] = readfrag(ldsA, wr * 128 + rt * 16 + ql, 1, g);
  }
#pragma unroll
  for (int ct = 0; ct < 4; ++ct) {
    B0a[ct] = readfrag(ldsB, wc * 64 + ct * 16 + ql, 0, g);
    B1a[ct] = readfrag(ldsB, wc * 64 + ct * 16 + ql, 1, g);
  }
  asm volatile("s_waitcnt vmcnt(0) lgkmcnt(0)" ::: "memory");
  __builtin_amdgcn_s_barrier();
  for (int T = 0; T < NT; T += 2) {
    GEMM_TILE(A0a, B0a, A1a, B1a, A0b, B0b, A1b, B1b,
              ldsA, ldsB, ldsA + 16384, ldsB + 16384, T);
    GEMM_TILE(A0b, B0b, A1b, B1b, A0a, B0a, A1a, B1a,
              ldsA + 16384, ldsB + 16384, ldsA, ldsB, T + 1);
  }
}

// ---------------------------------------------------------------------------
// K0: merged prep (unchanged).
__global__ __launch_bounds__(256) void k_prep(
    const float* __restrict__ x, const float* __restrict__ Wk,
    const float* __restrict__ Wq, const float* __restrict__ Wv,
    const float* __restrict__ Wa, const float* __restrict__ Wb,
    u16* __restrict__ xh, u16* __restrict__ wh,
    u16* __restrict__ waT_h, u16* __restrict__ waT_l,
    u16* __restrict__ wqT_h, u16* __restrict__ wqT_l,
    u16* __restrict__ wb_h, u16* __restrict__ wb_l,
    u16* __restrict__ wvT_h, u16* __restrict__ wvT_l,
    float* __restrict__ l) {
  const int bid = blockIdx.x, t = threadIdx.x;
  if (bid < 8192) {
    int i = bid * 256 + t;
    float4 v = ((const float4*)x)[i];
    ushort4 h;
    h.x = f2bf(v.x); h.y = f2bf(v.y); h.z = f2bf(v.z); h.w = f2bf(v.w);
    ((ushort4*)xh)[i] = h;
    return;
  }
  if (bid < 8704) {
    int i = (bid - 8192) * 256 + t;
    float4 v = ((const float4*)Wk)[i];
    ushort4 h;
    h.x = f2bf(v.x); h.y = f2bf(v.y); h.z = f2bf(v.z); h.w = f2bf(v.w);
    ((ushort4*)wh)[i] = h;
    return;
  }
  if (bid < 8960) {
    int i = (bid - 8704) * 256 + t;
    float4 v = ((const float4*)Wb)[i];
    ushort4 h, lo;
    h.x = f2bf(v.x); lo.x = f2bf(v.x - bf2f(h.x));
    h.y = f2bf(v.y); lo.y = f2bf(v.y - bf2f(h.y));
    h.z = f2bf(v.z); lo.z = f2bf(v.z - bf2f(h.z));
    h.w = f2bf(v.w); lo.w = f2bf(v.w - bf2f(h.w));
    ((ushort4*)wb_h)[i] = h;
    ((ushort4*)wb_l)[i] = lo;
    return;
  }
  if (bid >= 9280) {
    int i = (bid - 9280) * 256 + t;
    float4 z = {0.f, 0.f, 0.f, 0.f};
    ((float4*)l)[i] = z;
    return;
  }
  __shared__ float ftile[64][68];
  const int tb = bid - 8960;
  const float* src;
  u16 *dh, *dl;
  int S, m0, c0;
  if (tb < 64) {
    src = Wa; dh = waT_h; dl = waT_l; S = 512;
    m0 = (tb >> 3) * 64; c0 = (tb & 7) * 64;
  } else if (tb < 192) {
    int q = tb - 64;
    src = Wq; dh = wqT_h; dl = wqT_l; S = 1024;
    m0 = (q >> 4) * 64; c0 = (q & 15) * 64;
  } else {
    int q = tb - 192;
    src = Wv; dh = wvT_h; dl = wvT_l; S = 1024;
    m0 = (q >> 4) * 64; c0 = (q & 15) * 64;
  }
  {
    int i = t >> 4, j4 = (t & 15) * 4;
#pragma unroll
    for (int ii = 0; ii < 4; ++ii) {
      int row = i + ii * 16;
      float4 v = *(const float4*)&src[(size_t)(m0 + row) * S + c0 + j4];
      ftile[row][j4] = v.x; ftile[row][j4 + 1] = v.y;
      ftile[row][j4 + 2] = v.z; ftile[row][j4 + 3] = v.w;
    }
  }
  __syncthreads();
  {
    int oc = t >> 2, mc = (t & 3) * 16;
#pragma unroll
    for (int j = 0; j < 4; ++j) {
      int m = mc + j * 4;
      float v0 = ftile[m][oc], v1 = ftile[m + 1][oc];
      float v2 = ftile[m + 2][oc], v3 = ftile[m + 3][oc];
      ushort4 h, lo;
      h.x = f2bf(v0); lo.x = f2bf(v0 - bf2f(h.x));
      h.y = f2bf(v1); lo.y = f2bf(v1 - bf2f(h.y));
      h.z = f2bf(v2); lo.z = f2bf(v2 - bf2f(h.z));
      h.w = f2bf(v3); lo.w = f2bf(v3 - bf2f(h.w));
      size_t o = (size_t)(c0 + oc) * 512 + m0 + m;
      *(ushort4*)&dh[o] = h;
      *(ushort4*)&dl[o] = lo;
    }
  }
}

// ---------------------------------------------------------------------------
// K1: fold GEMMs, bf16x3 (unchanged).
__global__ __launch_bounds__(256, 2) void k_fold_mfma(
    const u16* __restrict__ waT_h, const u16* __restrict__ waT_l,
    const u16* __restrict__ wqT_h, const u16* __restrict__ wqT_l,
    const u16* __restrict__ wb_h, const u16* __restrict__ wb_l,
    const u16* __restrict__ wvT_h, const u16* __restrict__ wvT_l,
    u16* __restrict__ wh) {
  __shared__ u16 lah[8192], lal[8192], lbh[8192], lbl[8192];
  const int blk = blockIdx.x;
  const int which = blk >> 5;
  const int idx = blk & 31;
  const int r0 = (idx >> 3) * 128, c0 = (idx & 7) * 128;
  const u16* Ah = which ? wb_h : waT_h;
  const u16* Al = which ? wb_l : waT_l;
  const u16* Bh = which ? wvT_h : wqT_h;
  const u16* Bl = which ? wvT_l : wqT_l;
  const int obase = which ? 1024 : 512;
  const int t = threadIdx.x, lane = t & 63, w = t >> 6;
  const int wr = w >> 1, wc = w & 1, ql = lane & 15, g = lane >> 4;
  const f4 fzero = {0.f, 0.f, 0.f, 0.f};
  f4 acc[4][4];
#pragma unroll
  for (int i = 0; i < 4; ++i)
#pragma unroll
    for (int j = 0; j < 4; ++j) acc[i][j] = fzero;

  for (int ks = 0; ks < 8; ++ks) {
    __syncthreads();
    stage_tile(&Ah[(size_t)r0 * 512 + ks * 64], 512, lah, t);
    stage_tile(&Al[(size_t)r0 * 512 + ks * 64], 512, lal, t);
    stage_tile(&Bh[(size_t)c0 * 512 + ks * 64], 512, lbh, t);
    stage_tile(&Bl[(size_t)c0 * 512 + ks * 64], 512, lbl, t);
    __syncthreads();
#pragma unroll
    for (int kk = 0; kk < 2; ++kk) {
      b16x8 ah[4], al[4], bh[4], bl[4];
#pragma unroll
      for (int rt = 0; rt < 4; ++rt) {
        ah[rt] = readfrag(lah, wr * 64 + rt * 16 + ql, kk, g);
        al[rt] = readfrag(lal, wr * 64 + rt * 16 + ql, kk, g);
      }
#pragma unroll
      for (int ct = 0; ct < 4; ++ct) {
        bh[ct] = readfrag(lbh, wc * 64 + ct * 16 + ql, kk, g);
        bl[ct] = readfrag(lbl, wc * 64 + ct * 16 + ql, kk, g);
      }
#pragma unroll
      for (int rt = 0; rt < 4; ++rt)
#pragma unroll
        for (int ct = 0; ct < 4; ++ct)
          acc[rt][ct] = mfma3(ah[rt], al[rt], bh[ct], bl[ct], acc[rt][ct]);
    }
  }
#pragma unroll
  for (int rt = 0; rt < 4; ++rt) {
#pragma unroll
    for (int ct = 0; ct < 4; ++ct) {
      f4 v = acc[rt][ct];
      int col = c0 + wc * 64 + ct * 16 + ql;
      int rowb = r0 + wr * 64 + rt * 16 + g * 4;
#pragma unroll
      for (int r = 0; r < 4; ++r)
        wh[(size_t)(obase + rowb + r) * 1024 + col] = f2bf(v[r]);
    }
  }
}

// ---------------------------------------------------------------------------
// K2: projection GEMM. Grid 192: bid<128 -> KP (A=wh f-rows, B=xh s-rows,
// C[f][s]); bid>=128 -> U (A=xh s-rows, B=wh U-rows, C[s][f] -> ut[d][k]).
__global__ __launch_bounds__(512, 2) void k_proj(
    const u16* __restrict__ xh, const u16* __restrict__ wh,
    u16* __restrict__ kh, u16* __restrict__ ph, u16* __restrict__ ut) {
  __shared__ u16 lA[2 * 16384], lB[2 * 16384];   // 128 KB
  const int bid = blockIdx.x;
  const int t = threadIdx.x, lane = t & 63, w = t >> 6;
  const int wr = w >> 2, wc = w & 3, ql = lane & 15, g = lane >> 4;
  const f4 fzero = {0.f, 0.f, 0.f, 0.f};
  f4 acc[8][4];
#pragma unroll
  for (int i = 0; i < 8; ++i)
#pragma unroll
    for (int j = 0; j < 4; ++j) acc[i][j] = fzero;

  const bool kp = bid < 128;
  int rowt, colt;
  const u16 *Ab, *Bb;
  if (kp) {
    rowt = bid >> 5;                               // f-tile 0..3
    colt = (bid & 7) * 4 + ((bid >> 3) & 3);       // s-tile 0..31
    Ab = wh + (size_t)(rowt * 256) * 1024;
    Bb = xh + (size_t)(colt * 256) * 1024;
  } else {
    int b2 = bid - 128;
    rowt = (b2 & 7) * 4 + ((b2 >> 3) & 3);         // s-tile 0..31
    colt = b2 >> 5;                                // U f-tile 0..1
    Ab = xh + (size_t)(rowt * 256) * 1024;
    Bb = wh + (size_t)(1024 + colt * 256) * 1024;
  }
  const int sA = 1024, sB = 1024;
  gemm256_core<16>(Ab, sA, Bb, sB, lA, lB, t, wr, wc, ql, g, acc);

  if (kp) {
    // C[f][s]: f4 over 4 consecutive f at fixed s
#pragma unroll
    for (int rt = 0; rt < 8; ++rt) {
#pragma unroll
      for (int ct = 0; ct < 4; ++ct) {
        f4 v = acc[rt][ct];
        int f = rowt * 256 + wr * 128 + rt * 16 + g * 4;
        int s = colt * 256 + wc * 64 + ct * 16 + ql;
        ushort4 hh;
        hh.x = f2bf(v[0]); hh.y = f2bf(v[1]); hh.z = f2bf(v[2]); hh.w = f2bf(v[3]);
        if (f < 512) *(ushort4*)&kh[(size_t)s * 512 + f] = hh;
        else         *(ushort4*)&ph[(size_t)s * 512 + (f - 512)] = hh;
      }
    }
  } else {
    // C[s][f]: f4 over 4 consecutive s -> ut[b][d][k] ushort4 along k
#pragma unroll
    for (int rt = 0; rt < 8; ++rt) {
#pragma unroll
      for (int ct = 0; ct < 4; ++ct) {
        f4 v = acc[rt][ct];
        int d = colt * 256 + wc * 64 + ct * 16 + ql;
        int s = rowt * 256 + wr * 128 + rt * 16 + g * 4;
        int bb = s >> 11, k0 = s & 2047;
        ushort4 hh;
        hh.x = f2bf(v[0]); hh.y = f2bf(v[1]); hh.z = f2bf(v[2]); hh.w = f2bf(v[3]);
        *(ushort4*)&ut[((size_t)bb * 512 + d) * 2048 + k0] = hh;
      }
    }
  }
}

// ---------------------------------------------------------------------------
// K3: score GEMM, grid 256. A=K-rows, B=P-rows -> C[k][q];
// probs[b][q][k..k+3] = exp(C/T) ushort4; atomic row sums l[q].
__global__ __launch_bounds__(512, 2) void k_score(
    const u16* __restrict__ ph, const u16* __restrict__ kh,
    u16* __restrict__ probs, float* __restrict__ l) {
  constexpr float INVT = 0.04419417382415922f;  // 1/sqrt(512)
  __shared__ u16 lA[2 * 16384], lB[2 * 16384];
  const int bid = blockIdx.x;
  const int xcd = bid & 7, b = xcd >> 1, khalf = xcd & 1;
  const int idx = bid >> 3;                  // 0..31
  const int qtb = idx >> 2;                  // 0..7
  const int ktb = khalf * 4 + (idx & 3);     // 0..7
  const int q0 = qtb * 256, k0 = ktb * 256;
  const int t = threadIdx.x, lane = t & 63, w = t >> 6;
  const int wr = w >> 2, wc = w & 3, ql = lane & 15, g = lane >> 4;
  const f4 fzero = {0.f, 0.f, 0.f, 0.f};
  f4 acc[8][4];
#pragma unroll
  for (int i = 0; i < 8; ++i)
#pragma unroll
    for (int j = 0; j < 4; ++j) acc[i][j] = fzero;

  const u16* Ab = &kh[((size_t)b * 2048 + k0) * 512];
  const u16* Bb = &ph[((size_t)b * 2048 + q0) * 512];
  gemm256_core<8>(Ab, 512, Bb, 512, lA, lB, t, wr, wc, ql, g, acc);

  float lq[4] = {0.f, 0.f, 0.f, 0.f};
#pragma unroll
  for (int rt = 0; rt < 8; ++rt) {
    int kr = k0 + wr * 128 + rt * 16 + g * 4;
#pragma unroll
    for (int ct = 0; ct < 4; ++ct) {
      int q = q0 + wc * 64 + ct * 16 + ql;
      f4 a = acc[rt][ct];
      float p0 = __expf(a[0] * INVT), p1 = __expf(a[1] * INVT);
      float p2 = __expf(a[2] * INVT), p3 = __expf(a[3] * INVT);
      ushort4 hh;
      hh.x = f2bf(p0); hh.y = f2bf(p1); hh.z = f2bf(p2); hh.w = f2bf(p3);
      *(ushort4*)&probs[((size_t)b * 2048 + q) * 2048 + kr] = hh;
      lq[ct] += (p0 + p1) + (p2 + p3);
    }
  }
#pragma unroll
  for (int ct = 0; ct < 4; ++ct) {
    float s = lq[ct];
    s += __shfl_xor(s, 16);
    s += __shfl_xor(s, 32);
    if (lane < 16) atomicAdd(&l[b * 2048 + q0 + wc * 64 + ct * 16 + lane], s);
  }
}

// ---------------------------------------------------------------------------
// K4: output GEMM, grid 64, 256^2 core, NT=32.
// A = ut[d][k] (per batch), B = probs[q][k] -> C[d][q]; out[b][q][d] = v/l[q].
__global__ __launch_bounds__(512, 2) void k_out(
    const u16* __restrict__ ut, const u16* __restrict__ probs,
    const float* __restrict__ l, float* __restrict__ out) {
  __shared__ u16 lA[2 * 16384], lB[2 * 16384];
  const int bid = blockIdx.x;
  const int xcd = bid & 7, b = xcd >> 1, dt = xcd & 1;
  const int qt = bid >> 3;                   // 0..7
  const int d0 = dt * 256, q0 = qt * 256;
  const int t = threadIdx.x, lane = t & 63, w = t >> 6;
  const int wr = w >> 2, wc = w & 3, ql = lane & 15, g = lane >> 4;
  const f4 fzero = {0.f, 0.f, 0.f, 0.f};
  f4 acc[8][4];
#pragma unroll
  for (int i = 0; i < 8; ++i)
#pragma unroll
    for (int j = 0; j < 4; ++j) acc[i][j] = fzero;

  const u16* Ab = &ut[((size_t)b * 512 + d0) * 2048];
  const u16* Bb = &probs[((size_t)b * 2048 + q0) * 2048];
  gemm256_core<32>(Ab, 2048, Bb, 2048, lA, lB, t, wr, wc, ql, g, acc);

  // C[d][q]: f4 over 4 consecutive d at fixed q -> float4 store
#pragma unroll
  for (int ct = 0; ct < 4; ++ct) {
    int q = q0 + wc * 64 + ct * 16 + ql;
    float inv = 1.0f / l[b * 2048 + q];
    size_t orow = ((size_t)b * 2048 + q) * 512;
#pragma unroll
    for (int rt = 0; rt < 8; ++rt) {
      int d = d0 + wr * 128 + rt * 16 + g * 4;
      f4 v = acc[rt][ct] * inv;
      *(f4*)&out[orow + d] = v;
    }
  }
}

// ---------------------------------------------------------------------------
extern "C" void kernel_launch(void* const* d_in, const int* in_sizes, int n_in,
                              void* d_out, int out_size, void* d_ws, size_t ws_size,
                              hipStream_t stream) {
  const float* x = (const float*)d_in[0];
  const float* Wk = (const float*)d_in[1];
  const float* Wq = (const float*)d_in[2];
  const float* Wv = (const float*)d_in[3];
  const float* Wa = (const float*)d_in[4];
  const float* Wb = (const float*)d_in[5];
  float* out = (float*)d_out;

  char* ws = (char*)d_ws;
  size_t off = 0;
  auto alloc = [&](size_t bytes) -> void* {
    void* p = ws + off;
    off += (bytes + 255) & ~(size_t)255;
    return p;
  };
  u16* wh = (u16*)alloc((size_t)1536 * 1024 * 2);
  u16* xh = (u16*)alloc((size_t)8192 * 1024 * 2);
  u16* kh = (u16*)alloc((size_t)8192 * 512 * 2);
  u16* ph = (u16*)alloc((size_t)8192 * 512 * 2);
  u16* ut = (u16*)alloc((size_t)8192 * 512 * 2);
  u16* probs = (u16*)alloc((size_t)4 * 2048 * 2048 * 2);
  float* l = (float*)alloc(8192 * 4);
  u16* waT_h = (u16*)alloc((size_t)512 * 512 * 2);
  u16* waT_l = (u16*)alloc((size_t)512 * 512 * 2);
  u16* wqT_h = (u16*)alloc((size_t)1024 * 512 * 2);
  u16* wqT_l = (u16*)alloc((size_t)1024 * 512 * 2);
  u16* wb_h = (u16*)alloc((size_t)512 * 512 * 2);
  u16* wb_l = (u16*)alloc((size_t)512 * 512 * 2);
  u16* wvT_h = (u16*)alloc((size_t)1024 * 512 * 2);
  u16* wvT_l = (u16*)alloc((size_t)1024 * 512 * 2);
  (void)ws_size; (void)in_sizes; (void)n_in; (void)out_size;

  hipLaunchKernelGGL(k_prep, dim3(9288), dim3(256), 0, stream,
                     x, Wk, Wq, Wv, Wa, Wb, xh, wh,
                     waT_h, waT_l, wqT_h, wqT_l, wb_h, wb_l, wvT_h, wvT_l, l);
  hipLaunchKernelGGL(k_fold_mfma, dim3(64), dim3(256), 0, stream,
                     waT_h, waT_l, wqT_h, wqT_l, wb_h, wb_l, wvT_h, wvT_l, wh);
  hipLaunchKernelGGL(k_proj, dim3(192), dim3(512), 0, stream, xh, wh, kh, ph, ut);
  hipLaunchKernelGGL(k_score, dim3(256), dim3(512), 0, stream, ph, kh, probs, l);
  hipLaunchKernelGGL(k_out, dim3(64), dim3(512), 0, stream, ut, probs, l, out);
}

// Round 13
// 135.596 us; speedup vs baseline: 4.5493x; 4.5493x over previous
//
#include <hip/hip_runtime.h>

// SelfAttention_33852932227207 — MI355X, round 12 (resubmit; r12 bench died on
// an unresponsive container before launch — same pod as r10's infra failure).
// e = x^T (Wq^T Wa Wk) x / sqrt(512);  out = softmax(e) @ (x (Wb Wv)^T).
// r11 failed on VGPR spill (320 needed > 256; WRITE_SIZE 279MB = scratch).
// r12: same reads-one-half-ahead pipeline at spill-proof geometry:
//   block tile 256x128, 8 waves (4Mx2N), per-wave 64x64 -> acc 64 VGPR +
//   2 frag sets 64 VGPR ~ 160 total. One vmcnt(0)+barrier per K-tile;
//   ds_reads of the next half overlap the current register-only MFMA cluster;
//   stage of tile j+2 issues mid-tile into the freed buffer (2-half-step
//   flight time). Same per-accumulator MFMA order -> absmax unchanged.

typedef __attribute__((ext_vector_type(8))) short b16x8;
typedef __attribute__((ext_vector_type(4))) float f4;
typedef unsigned short u16;

#define DEVINL __device__ __forceinline__

DEVINL u16 f2bf(float f) {               // fp32 -> bf16 RNE
  unsigned int u = __float_as_uint(f);
  u = u + 0x7FFFu + ((u >> 16) & 1u);
  return (u16)(u >> 16);
}
DEVINL float bf2f(u16 h) { return __uint_as_float(((unsigned int)h) << 16); }

DEVINL f4 mfma_(b16x8 a, b16x8 b, f4 c) {
  return __builtin_amdgcn_mfma_f32_16x16x32_bf16(a, b, c, 0, 0, 0);
}
// bf16x3: (ah+al)*(bh+bl) ~= ah*bh + ah*bl + al*bh
DEVINL f4 mfma3(b16x8 ah, b16x8 al, b16x8 bh, b16x8 bl, f4 c) {
  c = mfma_(ah, bh, c);
  c = mfma_(ah, bl, c);
  c = mfma_(al, bh, c);
  return c;
}
DEVINL void gload16(const u16* g, u16* l) {
  __builtin_amdgcn_global_load_lds(
      (const __attribute__((address_space(1))) void*)g,
      (__attribute__((address_space(3))) void*)l, 16, 0, 0);
}

// ---- 16B-chunk XOR swizzle tile helpers (r5-proven, bank-conflict=0).
DEVINL void stage_tile(const u16* __restrict__ gbase, int rstride,
                       u16* __restrict__ lds, int t) {      // 128x64, 256 thr
#pragma unroll
  for (int r = 0; r < 4; ++r) {
    int cp = r * 256 + t;
    int row = cp >> 3, j = cp & 7;
    int jj = j ^ (row & 7);
    gload16(&gbase[(size_t)row * rstride + jj * 8], &lds[cp * 8]);
  }
}
DEVINL void stageA256(const u16* __restrict__ gbase, int rstride,
                      u16* __restrict__ lds, int t) {       // 256x64, 512 thr
#pragma unroll
  for (int r = 0; r < 4; ++r) {
    int cp = r * 512 + t;                // 2048 chunks
    int row = cp >> 3, j = cp & 7;
    int jj = j ^ (row & 7);
    gload16(&gbase[(size_t)row * rstride + jj * 8], &lds[cp * 8]);
  }
}
DEVINL void stageB128(const u16* __restrict__ gbase, int rstride,
                      u16* __restrict__ lds, int t) {       // 128x64, 512 thr
#pragma unroll
  for (int r = 0; r < 2; ++r) {
    int cp = r * 512 + t;                // 1024 chunks
    int row = cp >> 3, j = cp & 7;
    int jj = j ^ (row & 7);
    gload16(&gbase[(size_t)row * rstride + jj * 8], &lds[cp * 8]);
  }
}
DEVINL b16x8 readfrag(const u16* __restrict__ lds, int row, int kk, int g) {
  int chunk = row * 8 + ((kk * 4 + g) ^ (row & 7));
  return *(const b16x8*)&lds[chunk * 8];
}

// ---- 256x128 BK=64 8-wave GEMM core, reads-one-half-ahead pipeline.
// acc[4][4] per wave (64x64). One vmcnt(0)+barrier per K-tile.
// C[m][n]: m = wr*64+rt*16+g*4+reg (A row), n = wc*64+ct*16+ql (B row).
template <int NT>
DEVINL void gemm_core(const u16* __restrict__ Ab, int sA,
                      const u16* __restrict__ Bb, int sB,
                      u16* __restrict__ ldsA, u16* __restrict__ ldsB,
                      int t, int wr, int wc, int ql, int g, f4 acc[4][4]) {
  b16x8 fa[4], fb[4];   // even-half frags (tile j, kk0)
  b16x8 ga[4], gb[4];   // odd-half frags (tile j, kk1)
  // prologue: tile0 -> buf0, tile1 -> buf1 (6 loads/thread each)
  stageA256(Ab, sA, ldsA, t);
  stageB128(Bb, sB, ldsB, t);
  stageA256(Ab + 64, sA, ldsA + 16384, t);
  stageB128(Bb + 64, sB, ldsB + 8192, t);
  asm volatile("s_waitcnt vmcnt(6)" ::: "memory");   // tile0 arrived
  __builtin_amdgcn_s_barrier();
  asm volatile("" ::: "memory");
  u16 *cA = ldsA, *cB = ldsB, *nA = ldsA + 16384, *nB = ldsB + 8192;
#pragma unroll
  for (int i = 0; i < 4; ++i) {
    fa[i] = readfrag(cA, wr * 64 + i * 16 + ql, 0, g);
    fb[i] = readfrag(cB, wc * 64 + i * 16 + ql, 0, g);
  }
  for (int j = 0; j < NT; ++j) {
    // ---- even half: read (tile j, kk1) ; MFMA (tile j, kk0) from regs
#pragma unroll
    for (int i = 0; i < 4; ++i) {
      ga[i] = readfrag(cA, wr * 64 + i * 16 + ql, 1, g);
      gb[i] = readfrag(cB, wc * 64 + i * 16 + ql, 1, g);
    }
    __builtin_amdgcn_s_setprio(1);
#pragma unroll
    for (int rt = 0; rt < 4; ++rt)
#pragma unroll
      for (int ct = 0; ct < 4; ++ct)
        acc[rt][ct] = mfma_(fa[rt], fb[ct], acc[rt][ct]);
    __builtin_amdgcn_s_setprio(0);
    // ---- tile fence: validate tile j+1 (staged 2 half-steps ago)
    asm volatile("s_waitcnt vmcnt(0)" ::: "memory");
    __builtin_amdgcn_s_barrier();
    asm volatile("" ::: "memory");
    // ---- odd half: read (tile j+1, kk0) ; stage tile j+2 into freed buf ;
    //      MFMA (tile j, kk1) from regs
    if (j + 1 < NT) {
#pragma unroll
      for (int i = 0; i < 4; ++i) {
        fa[i] = readfrag(nA, wr * 64 + i * 16 + ql, 0, g);
        fb[i] = readfrag(nB, wc * 64 + i * 16 + ql, 0, g);
      }
    }
    if (j + 2 < NT) {
      stageA256(Ab + (j + 2) * 64, sA, cA, t);
      stageB128(Bb + (j + 2) * 64, sB, cB, t);
    }
    __builtin_amdgcn_s_setprio(1);
#pragma unroll
    for (int rt = 0; rt < 4; ++rt)
#pragma unroll
      for (int ct = 0; ct < 4; ++ct)
        acc[rt][ct] = mfma_(ga[rt], gb[ct], acc[rt][ct]);
    __builtin_amdgcn_s_setprio(0);
    u16* tmp = cA; cA = nA; nA = tmp;
    tmp = cB; cB = nB; nB = tmp;
  }
}

// ---------------------------------------------------------------------------
// K0: merged prep (unchanged).
__global__ __launch_bounds__(256) void k_prep(
    const float* __restrict__ x, const float* __restrict__ Wk,
    const float* __restrict__ Wq, const float* __restrict__ Wv,
    const float* __restrict__ Wa, const float* __restrict__ Wb,
    u16* __restrict__ xh, u16* __restrict__ wh,
    u16* __restrict__ waT_h, u16* __restrict__ waT_l,
    u16* __restrict__ wqT_h, u16* __restrict__ wqT_l,
    u16* __restrict__ wb_h, u16* __restrict__ wb_l,
    u16* __restrict__ wvT_h, u16* __restrict__ wvT_l,
    float* __restrict__ l) {
  const int bid = blockIdx.x, t = threadIdx.x;
  if (bid < 8192) {
    int i = bid * 256 + t;
    float4 v = ((const float4*)x)[i];
    ushort4 h;
    h.x = f2bf(v.x); h.y = f2bf(v.y); h.z = f2bf(v.z); h.w = f2bf(v.w);
    ((ushort4*)xh)[i] = h;
    return;
  }
  if (bid < 8704) {
    int i = (bid - 8192) * 256 + t;
    float4 v = ((const float4*)Wk)[i];
    ushort4 h;
    h.x = f2bf(v.x); h.y = f2bf(v.y); h.z = f2bf(v.z); h.w = f2bf(v.w);
    ((ushort4*)wh)[i] = h;
    return;
  }
  if (bid < 8960) {
    int i = (bid - 8704) * 256 + t;
    float4 v = ((const float4*)Wb)[i];
    ushort4 h, lo;
    h.x = f2bf(v.x); lo.x = f2bf(v.x - bf2f(h.x));
    h.y = f2bf(v.y); lo.y = f2bf(v.y - bf2f(h.y));
    h.z = f2bf(v.z); lo.z = f2bf(v.z - bf2f(h.z));
    h.w = f2bf(v.w); lo.w = f2bf(v.w - bf2f(h.w));
    ((ushort4*)wb_h)[i] = h;
    ((ushort4*)wb_l)[i] = lo;
    return;
  }
  if (bid >= 9280) {
    int i = (bid - 9280) * 256 + t;
    float4 z = {0.f, 0.f, 0.f, 0.f};
    ((float4*)l)[i] = z;
    return;
  }
  __shared__ float ftile[64][68];
  const int tb = bid - 8960;
  const float* src;
  u16 *dh, *dl;
  int S, m0, c0;
  if (tb < 64) {
    src = Wa; dh = waT_h; dl = waT_l; S = 512;
    m0 = (tb >> 3) * 64; c0 = (tb & 7) * 64;
  } else if (tb < 192) {
    int q = tb - 64;
    src = Wq; dh = wqT_h; dl = wqT_l; S = 1024;
    m0 = (q >> 4) * 64; c0 = (q & 15) * 64;
  } else {
    int q = tb - 192;
    src = Wv; dh = wvT_h; dl = wvT_l; S = 1024;
    m0 = (q >> 4) * 64; c0 = (q & 15) * 64;
  }
  {
    int i = t >> 4, j4 = (t & 15) * 4;
#pragma unroll
    for (int ii = 0; ii < 4; ++ii) {
      int row = i + ii * 16;
      float4 v = *(const float4*)&src[(size_t)(m0 + row) * S + c0 + j4];
      ftile[row][j4] = v.x; ftile[row][j4 + 1] = v.y;
      ftile[row][j4 + 2] = v.z; ftile[row][j4 + 3] = v.w;
    }
  }
  __syncthreads();
  {
    int oc = t >> 2, mc = (t & 3) * 16;
#pragma unroll
    for (int j = 0; j < 4; ++j) {
      int m = mc + j * 4;
      float v0 = ftile[m][oc], v1 = ftile[m + 1][oc];
      float v2 = ftile[m + 2][oc], v3 = ftile[m + 3][oc];
      ushort4 h, lo;
      h.x = f2bf(v0); lo.x = f2bf(v0 - bf2f(h.x));
      h.y = f2bf(v1); lo.y = f2bf(v1 - bf2f(h.y));
      h.z = f2bf(v2); lo.z = f2bf(v2 - bf2f(h.z));
      h.w = f2bf(v3); lo.w = f2bf(v3 - bf2f(h.w));
      size_t o = (size_t)(c0 + oc) * 512 + m0 + m;
      *(ushort4*)&dh[o] = h;
      *(ushort4*)&dl[o] = lo;
    }
  }
}

// ---------------------------------------------------------------------------
// K1: fold GEMMs, bf16x3 (unchanged).
__global__ __launch_bounds__(256, 2) void k_fold_mfma(
    const u16* __restrict__ waT_h, const u16* __restrict__ waT_l,
    const u16* __restrict__ wqT_h, const u16* __restrict__ wqT_l,
    const u16* __restrict__ wb_h, const u16* __restrict__ wb_l,
    const u16* __restrict__ wvT_h, const u16* __restrict__ wvT_l,
    u16* __restrict__ wh) {
  __shared__ u16 lah[8192], lal[8192], lbh[8192], lbl[8192];
  const int blk = blockIdx.x;
  const int which = blk >> 5;
  const int idx = blk & 31;
  const int r0 = (idx >> 3) * 128, c0 = (idx & 7) * 128;
  const u16* Ah = which ? wb_h : waT_h;
  const u16* Al = which ? wb_l : waT_l;
  const u16* Bh = which ? wvT_h : wqT_h;
  const u16* Bl = which ? wvT_l : wqT_l;
  const int obase = which ? 1024 : 512;
  const int t = threadIdx.x, lane = t & 63, w = t >> 6;
  const int wr = w >> 1, wc = w & 1, ql = lane & 15, g = lane >> 4;
  const f4 fzero = {0.f, 0.f, 0.f, 0.f};
  f4 acc[4][4];
#pragma unroll
  for (int i = 0; i < 4; ++i)
#pragma unroll
    for (int j = 0; j < 4; ++j) acc[i][j] = fzero;

  for (int ks = 0; ks < 8; ++ks) {
    __syncthreads();
    stage_tile(&Ah[(size_t)r0 * 512 + ks * 64], 512, lah, t);
    stage_tile(&Al[(size_t)r0 * 512 + ks * 64], 512, lal, t);
    stage_tile(&Bh[(size_t)c0 * 512 + ks * 64], 512, lbh, t);
    stage_tile(&Bl[(size_t)c0 * 512 + ks * 64], 512, lbl, t);
    __syncthreads();
#pragma unroll
    for (int kk = 0; kk < 2; ++kk) {
      b16x8 ah[4], al[4], bh[4], bl[4];
#pragma unroll
      for (int rt = 0; rt < 4; ++rt) {
        ah[rt] = readfrag(lah, wr * 64 + rt * 16 + ql, kk, g);
        al[rt] = readfrag(lal, wr * 64 + rt * 16 + ql, kk, g);
      }
#pragma unroll
      for (int ct = 0; ct < 4; ++ct) {
        bh[ct] = readfrag(lbh, wc * 64 + ct * 16 + ql, kk, g);
        bl[ct] = readfrag(lbl, wc * 64 + ct * 16 + ql, kk, g);
      }
#pragma unroll
      for (int rt = 0; rt < 4; ++rt)
#pragma unroll
        for (int ct = 0; ct < 4; ++ct)
          acc[rt][ct] = mfma3(ah[rt], al[rt], bh[ct], bl[ct], acc[rt][ct]);
    }
  }
#pragma unroll
  for (int rt = 0; rt < 4; ++rt) {
#pragma unroll
    for (int ct = 0; ct < 4; ++ct) {
      f4 v = acc[rt][ct];
      int col = c0 + wc * 64 + ct * 16 + ql;
      int rowb = r0 + wr * 64 + rt * 16 + g * 4;
#pragma unroll
      for (int r = 0; r < 4; ++r)
        wh[(size_t)(obase + rowb + r) * 1024 + col] = f2bf(v[r]);
    }
  }
}

// ---------------------------------------------------------------------------
// K2: projection GEMM, 256x128 tiles. Grid 384:
//  bid<256: KP. A=wh f-rows (Mt 0..3), B=xh s-rows (Nt 0..63) -> C[f][s].
//  bid>=256: U. A=xh s-rows (Mt 0..31), B=wh U-rows (Nt 0..3) -> C[s][d].
__global__ __launch_bounds__(512, 2) void k_proj(
    const u16* __restrict__ xh, const u16* __restrict__ wh,
    u16* __restrict__ kh, u16* __restrict__ ph, u16* __restrict__ ut) {
  __shared__ u16 lA[2 * 16384], lB[2 * 8192];    // 96 KB
  const int bid = blockIdx.x;
  const int t = threadIdx.x, lane = t & 63, w = t >> 6;
  const int wr = w >> 1, wc = w & 1, ql = lane & 15, g = lane >> 4;
  const f4 fzero = {0.f, 0.f, 0.f, 0.f};
  f4 acc[4][4];
#pragma unroll
  for (int i = 0; i < 4; ++i)
#pragma unroll
    for (int j = 0; j < 4; ++j) acc[i][j] = fzero;

  const bool kp = bid < 256;
  int Mt, Nt;
  const u16 *Ab, *Bb;
  if (kp) {
    Mt = bid >> 6;                         // 0..3
    Nt = bid & 63;                         // 0..63
    Ab = wh + (size_t)(Mt * 256) * 1024;
    Bb = xh + (size_t)(Nt * 128) * 1024;
  } else {
    int b2 = bid - 256;
    Mt = b2 >> 2;                          // 0..31
    Nt = b2 & 3;                           // 0..3
    Ab = xh + (size_t)(Mt * 256) * 1024;
    Bb = wh + (size_t)(1024 + Nt * 128) * 1024;
  }
  gemm_core<16>(Ab, 1024, Bb, 1024, lA, lB, t, wr, wc, ql, g, acc);

  if (kp) {
    // C[f][s]: f4 over 4 consecutive f at fixed s
#pragma unroll
    for (int rt = 0; rt < 4; ++rt) {
#pragma unroll
      for (int ct = 0; ct < 4; ++ct) {
        f4 v = acc[rt][ct];
        int f = Mt * 256 + wr * 64 + rt * 16 + g * 4;
        int s = Nt * 128 + wc * 64 + ct * 16 + ql;
        ushort4 hh;
        hh.x = f2bf(v[0]); hh.y = f2bf(v[1]); hh.z = f2bf(v[2]); hh.w = f2bf(v[3]);
        if (f < 512) *(ushort4*)&kh[(size_t)s * 512 + f] = hh;
        else         *(ushort4*)&ph[(size_t)s * 512 + (f - 512)] = hh;
      }
    }
  } else {
    // C[s][d]: f4 over 4 consecutive s -> ut[b][d][k] ushort4 along k
#pragma unroll
    for (int rt = 0; rt < 4; ++rt) {
#pragma unroll
      for (int ct = 0; ct < 4; ++ct) {
        f4 v = acc[rt][ct];
        int s = Mt * 256 + wr * 64 + rt * 16 + g * 4;
        int d = Nt * 128 + wc * 64 + ct * 16 + ql;
        int bb = s >> 11, k0 = s & 2047;
        ushort4 hh;
        hh.x = f2bf(v[0]); hh.y = f2bf(v[1]); hh.z = f2bf(v[2]); hh.w = f2bf(v[3]);
        *(ushort4*)&ut[((size_t)bb * 512 + d) * 2048 + k0] = hh;
      }
    }
  }
}

// ---------------------------------------------------------------------------
// K3: score GEMM, grid 512 = b(4) x Mt(8, k-tiles 256) x Nt(16, q-tiles 128).
// A=K-rows, B=P-rows -> C[k][q]; probs=exp(C/T) ushort4; atomic row sums l[q].
__global__ __launch_bounds__(512, 2) void k_score(
    const u16* __restrict__ ph, const u16* __restrict__ kh,
    u16* __restrict__ probs, float* __restrict__ l) {
  constexpr float INVT = 0.04419417382415922f;  // 1/sqrt(512)
  __shared__ u16 lA[2 * 16384], lB[2 * 8192];
  const int bid = blockIdx.x;
  const int b = bid >> 7, rem = bid & 127;
  const int Mt = rem >> 4, Nt = rem & 15;
  const int k0b = Mt * 256, q0b = Nt * 128;
  const int t = threadIdx.x, lane = t & 63, w = t >> 6;
  const int wr = w >> 1, wc = w & 1, ql = lane & 15, g = lane >> 4;
  const f4 fzero = {0.f, 0.f, 0.f, 0.f};
  f4 acc[4][4];
#pragma unroll
  for (int i = 0; i < 4; ++i)
#pragma unroll
    for (int j = 0; j < 4; ++j) acc[i][j] = fzero;

  const u16* Ab = &kh[((size_t)b * 2048 + k0b) * 512];
  const u16* Bb = &ph[((size_t)b * 2048 + q0b) * 512];
  gemm_core<8>(Ab, 512, Bb, 512, lA, lB, t, wr, wc, ql, g, acc);

  float lq[4] = {0.f, 0.f, 0.f, 0.f};
#pragma unroll
  for (int rt = 0; rt < 4; ++rt) {
    int kr = k0b + wr * 64 + rt * 16 + g * 4;
#pragma unroll
    for (int ct = 0; ct < 4; ++ct) {
      int q = q0b + wc * 64 + ct * 16 + ql;
      f4 a = acc[rt][ct];
      float p0 = __expf(a[0] * INVT), p1 = __expf(a[1] * INVT);
      float p2 = __expf(a[2] * INVT), p3 = __expf(a[3] * INVT);
      ushort4 hh;
      hh.x = f2bf(p0); hh.y = f2bf(p1); hh.z = f2bf(p2); hh.w = f2bf(p3);
      *(ushort4*)&probs[((size_t)b * 2048 + q) * 2048 + kr] = hh;
      lq[ct] += (p0 + p1) + (p2 + p3);
    }
  }
#pragma unroll
  for (int ct = 0; ct < 4; ++ct) {
    float s = lq[ct];
    s += __shfl_xor(s, 16);
    s += __shfl_xor(s, 32);
    if (lane < 16) atomicAdd(&l[b * 2048 + q0b + wc * 64 + ct * 16 + lane], s);
  }
}

// ---------------------------------------------------------------------------
// K4: output GEMM, grid 128 = b(4) x Mt(2, d-tiles 256) x Nt(16, q-tiles 128).
// A=ut[d][k], B=probs[q][k] -> C[d][q]; out[b][q][d] = v / l[q], float4.
__global__ __launch_bounds__(512, 2) void k_out(
    const u16* __restrict__ ut, const u16* __restrict__ probs,
    const float* __restrict__ l, float* __restrict__ out) {
  __shared__ u16 lA[2 * 16384], lB[2 * 8192];
  const int bid = blockIdx.x;
  const int b = bid >> 5, rem = bid & 31;
  const int Mt = rem >> 4, Nt = rem & 15;
  const int d0 = Mt * 256, q0 = Nt * 128;
  const int t = threadIdx.x, lane = t & 63, w = t >> 6;
  const int wr = w >> 1, wc = w & 1, ql = lane & 15, g = lane >> 4;
  const f4 fzero = {0.f, 0.f, 0.f, 0.f};
  f4 acc[4][4];
#pragma unroll
  for (int i = 0; i < 4; ++i)
#pragma unroll
    for (int j = 0; j < 4; ++j) acc[i][j] = fzero;

  const u16* Ab = &ut[((size_t)b * 512 + d0) * 2048];
  const u16* Bb = &probs[((size_t)b * 2048 + q0) * 2048];
  gemm_core<32>(Ab, 2048, Bb, 2048, lA, lB, t, wr, wc, ql, g, acc);

#pragma unroll
  for (int ct = 0; ct < 4; ++ct) {
    int q = q0 + wc * 64 + ct * 16 + ql;
    float inv = 1.0f / l[b * 2048 + q];
    size_t orow = ((size_t)b * 2048 + q) * 512;
#pragma unroll
    for (int rt = 0; rt < 4; ++rt) {
      int d = d0 + wr * 64 + rt * 16 + g * 4;
      f4 v = acc[rt][ct] * inv;
      *(f4*)&out[orow + d] = v;
    }
  }
}

// ---------------------------------------------------------------------------
extern "C" void kernel_launch(void* const* d_in, const int* in_sizes, int n_in,
                              void* d_out, int out_size, void* d_ws, size_t ws_size,
                              hipStream_t stream) {
  const float* x = (const float*)d_in[0];
  const float* Wk = (const float*)d_in[1];
  const float* Wq = (const float*)d_in[2];
  const float* Wv = (const float*)d_in[3];
  const float* Wa = (const float*)d_in[4];
  const float* Wb = (const float*)d_in[5];
  float* out = (float*)d_out;

  char* ws = (char*)d_ws;
  size_t off = 0;
  auto alloc = [&](size_t bytes) -> void* {
    void* p = ws + off;
    off += (bytes + 255) & ~(size_t)255;
    return p;
  };
  u16* wh = (u16*)alloc((size_t)1536 * 1024 * 2);
  u16* xh = (u16*)alloc((size_t)8192 * 1024 * 2);
  u16* kh = (u16*)alloc((size_t)8192 * 512 * 2);
  u16* ph = (u16*)alloc((size_t)8192 * 512 * 2);
  u16* ut = (u16*)alloc((size_t)8192 * 512 * 2);
  u16* probs = (u16*)alloc((size_t)4 * 2048 * 2048 * 2);
  float* l = (float*)alloc(8192 * 4);
  u16* waT_h = (u16*)alloc((size_t)512 * 512 * 2);
  u16* waT_l = (u16*)alloc((size_t)512 * 512 * 2);
  u16* wqT_h = (u16*)alloc((size_t)1024 * 512 * 2);
  u16* wqT_l = (u16*)alloc((size_t)1024 * 512 * 2);
  u16* wb_h = (u16*)alloc((size_t)512 * 512 * 2);
  u16* wb_l = (u16*)alloc((size_t)512 * 512 * 2);
  u16* wvT_h = (u16*)alloc((size_t)1024 * 512 * 2);
  u16* wvT_l = (u16*)alloc((size_t)1024 * 512 * 2);
  (void)ws_size; (void)in_sizes; (void)n_in; (void)out_size;

  hipLaunchKernelGGL(k_prep, dim3(9288), dim3(256), 0, stream,
                     x, Wk, Wq, Wv, Wa, Wb, xh, wh,
                     waT_h, waT_l, wqT_h, wqT_l, wb_h, wb_l, wvT_h, wvT_l, l);
  hipLaunchKernelGGL(k_fold_mfma, dim3(64), dim3(256), 0, stream,
                     waT_h, waT_l, wqT_h, wqT_l, wb_h, wb_l, wvT_h, wvT_l, wh);
  hipLaunchKernelGGL(k_proj, dim3(384), dim3(512), 0, stream, xh, wh, kh, ph, ut);
  hipLaunchKernelGGL(k_score, dim3(512), dim3(512), 0, stream, ph, kh, probs, l);
  hipLaunchKernelGGL(k_out, dim3(128), dim3(512), 0, stream, ut, probs, l, out);
}